// Round 1
// baseline (8473.833 us; speedup 1.0000x reference)
//
#include <hip/hip_runtime.h>
#include <math.h>

#define NNODES 100000
#define NEDGES 1600000
#define CH 64
#define CH2 128
#define NLAYERS 3

// ---------------- degree / norm precompute ----------------

__global__ void count_deg_kernel(const int* __restrict__ dst, float* __restrict__ deg, int E) {
    int t = blockIdx.x * blockDim.x + threadIdx.x;
    if (t < E) atomicAdd(&deg[dst[t]], 1.0f);
}

__global__ void dinv_kernel(const float* __restrict__ deg, float* __restrict__ dinv, int n) {
    int t = blockIdx.x * blockDim.x + threadIdx.x;
    if (t < n) dinv[t] = rsqrtf(deg[t] + 1.0f);   // +1 for self-loop
}

__global__ void coef_kernel(const int* __restrict__ src, const int* __restrict__ dst,
                            const float* __restrict__ dinv, float* __restrict__ coef, int E) {
    int t = blockIdx.x * blockDim.x + threadIdx.x;
    if (t < E) coef[t] = dinv[src[t]] * dinv[dst[t]];
}

// ---------------- GEMM: h[N,128] = x[N,64] @ W[64,128] ----------------
// block = 256 threads, each block computes a 16-row x 128-col tile.
// W (64*128 floats = 32KB) staged in LDS once per block; x tile (16x64 = 4KB) in LDS.

__global__ __launch_bounds__(256) void gemm_kernel(const float* __restrict__ x,
                                                   const float* __restrict__ W,
                                                   float* __restrict__ h) {
    __shared__ float Wl[CH * CH2];   // 32 KB
    __shared__ float Xl[16 * CH];    // 4 KB
    int t = threadIdx.x;

    // stage W: 2048 float4 / 256 threads = 8 each
    const float4* W4 = (const float4*)W;
    float4* Wl4 = (float4*)Wl;
#pragma unroll
    for (int i = 0; i < 8; ++i) Wl4[t + 256 * i] = W4[t + 256 * i];

    // stage x tile: 16 rows * 64 = 1024 floats = 256 float4, one per thread
    int row0 = blockIdx.x * 16;
    ((float4*)Xl)[t] = ((const float4*)(x + (size_t)row0 * CH))[t];
    __syncthreads();

    int col = t & 127;       // 0..127
    int rg  = t >> 7;        // 0..1 ; thread handles rows rg*8 .. rg*8+7
    float acc[8];
#pragma unroll
    for (int i = 0; i < 8; ++i) acc[i] = 0.0f;

#pragma unroll 4
    for (int k = 0; k < CH; ++k) {
        float w = Wl[k * CH2 + col];
#pragma unroll
        for (int i = 0; i < 8; ++i)
            acc[i] += Xl[(rg * 8 + i) * CH + k] * w;
    }

#pragma unroll
    for (int i = 0; i < 8; ++i)
        h[((size_t)row0 + rg * 8 + i) * CH2 + col] = acc[i];
}

// ---------------- edge scatter: agg[dst] += h[src] * coef ----------------
// one thread per (edge, 4-channel group): 32 threads share an edge.

__global__ __launch_bounds__(256) void scatter_kernel(const int* __restrict__ src,
                                                      const int* __restrict__ dst,
                                                      const float* __restrict__ coef,
                                                      const float* __restrict__ h,
                                                      float* __restrict__ agg) {
    long long t = (long long)blockIdx.x * blockDim.x + threadIdx.x;
    if (t >= (long long)NEDGES * 32) return;
    int e = (int)(t >> 5);
    int q = (int)(t & 31);
    int s = src[e];
    int d = dst[e];
    float c = coef[e];
    float4 hv = ((const float4*)h)[(size_t)s * 32 + q];
    float* ap = agg + (size_t)d * CH2 + q * 4;
    atomicAdd(ap + 0, hv.x * c);
    atomicAdd(ap + 1, hv.y * c);
    atomicAdd(ap + 2, hv.z * c);
    atomicAdd(ap + 3, hv.w * c);
}

// ---------------- finalize: bias + self-loop + GLU + residual ----------------

__global__ __launch_bounds__(256) void finalize_kernel(const float* __restrict__ agg,
                                                       const float* __restrict__ h,
                                                       const float* __restrict__ b,
                                                       const float* __restrict__ dinv,
                                                       const float* __restrict__ xold,
                                                       float* __restrict__ xnew) {
    int t = blockIdx.x * blockDim.x + threadIdx.x;
    if (t >= NNODES * CH) return;
    int i = t >> 6;
    int c = t & 63;
    float dv = dinv[i];
    float d2 = dv * dv;
    size_t base = (size_t)i * CH2;
    float av = agg[base + c]      + h[base + c]      * d2 + b[c];
    float gv = agg[base + 64 + c] + h[base + 64 + c] * d2 + b[64 + c];
    float sg = 1.0f / (1.0f + expf(-gv));
    xnew[t] = av * sg + xold[t];
}

// ---------------- launch ----------------

extern "C" void kernel_launch(void* const* d_in, const int* in_sizes, int n_in,
                              void* d_out, int out_size, void* d_ws, size_t ws_size,
                              hipStream_t stream) {
    const float* x_in = (const float*)d_in[0];              // [N,64]
    const float* Ws   = (const float*)d_in[1];              // [3,64,128]
    const float* bs   = (const float*)d_in[2];              // [3,128]
    const int*   ei   = (const int*)d_in[3];                // [2,E]
    const int* src = ei;
    const int* dst = ei + NEDGES;

    float* ws = (float*)d_ws;
    float* deg  = ws;                                       // N
    float* dinv = deg  + NNODES;                            // N
    float* coef = ws + 2 * NNODES;                          // E  (offset 200000: 16B-aligned)
    float* h    = ws + 1800000;                             // N*128 (16B-aligned offset)
    float* agg  = h + (size_t)NNODES * CH2;                 // N*128
    float* xbuf = agg + (size_t)NNODES * CH2;               // N*64

    // degree + norms (once; reused by all layers)
    hipMemsetAsync(deg, 0, NNODES * sizeof(float), stream);
    count_deg_kernel<<<(NEDGES + 255) / 256, 256, 0, stream>>>(dst, deg, NEDGES);
    dinv_kernel<<<(NNODES + 255) / 256, 256, 0, stream>>>(deg, dinv, NNODES);
    coef_kernel<<<(NEDGES + 255) / 256, 256, 0, stream>>>(src, dst, dinv, coef, NEDGES);

    const float* xl = x_in;
    for (int l = 0; l < NLAYERS; ++l) {
        const float* W = Ws + (size_t)l * CH * CH2;
        const float* b = bs + (size_t)l * CH2;
        float* xout = (l == NLAYERS - 1) ? (float*)d_out : xbuf;

        hipMemsetAsync(agg, 0, (size_t)NNODES * CH2 * sizeof(float), stream);
        gemm_kernel<<<NNODES / 16, 256, 0, stream>>>(xl, W, h);
        scatter_kernel<<<(int)(((long long)NEDGES * 32) / 256), 256, 0, stream>>>(src, dst, coef, h, agg);
        finalize_kernel<<<(NNODES * CH + 255) / 256, 256, 0, stream>>>(agg, h, b, dinv, xl, xout);

        xl = xout;   // layer 1 runs in-place on xbuf (finalize is elementwise-aligned: safe)
    }
}

// Round 2
// 1119.728 us; speedup vs baseline: 7.5678x; 7.5678x over previous
//
#include <hip/hip_runtime.h>
#include <math.h>

#define NNODES 100000
#define NEDGES 1600000
#define CH 64
#define CH2 128
#define NLAYERS 3
#define SCAN_THREADS 1024
#define SEG ((NNODES + SCAN_THREADS - 1) / SCAN_THREADS)   // 98

// ---------------- CSR build: histogram over dst ----------------

__global__ void hist_kernel(const int* __restrict__ dst, int* __restrict__ cnt, int E) {
    int t = blockIdx.x * blockDim.x + threadIdx.x;
    if (t < E) atomicAdd(&cnt[dst[t]], 1);
}

__global__ void dinv_kernel(const int* __restrict__ cnt, float* __restrict__ dinv, int n) {
    int t = blockIdx.x * blockDim.x + threadIdx.x;
    if (t < n) dinv[t] = rsqrtf((float)cnt[t] + 1.0f);   // +1 self-loop
}

// single-workgroup scan over N=100k: writes rowptr (exclusive) and cursor copy
__global__ __launch_bounds__(SCAN_THREADS) void scan_kernel(const int* __restrict__ cnt,
                                                            int* __restrict__ rowptr,
                                                            int* __restrict__ cursor) {
    __shared__ int s[SCAN_THREADS];
    int t = threadIdx.x;
    int base = t * SEG;
    int sum = 0;
    for (int i = 0; i < SEG; ++i) {
        int idx = base + i;
        if (idx < NNODES) sum += cnt[idx];
    }
    s[t] = sum;
    __syncthreads();
    for (int off = 1; off < SCAN_THREADS; off <<= 1) {
        int v = 0;
        if (t >= off) v = s[t - off];
        __syncthreads();
        if (t >= off) s[t] += v;
        __syncthreads();
    }
    int run = s[t] - sum;   // exclusive prefix for this thread's segment
    for (int i = 0; i < SEG; ++i) {
        int idx = base + i;
        if (idx < NNODES) {
            rowptr[idx] = run;
            cursor[idx] = run;
            run += cnt[idx];
        }
    }
    if (t == 0) rowptr[NNODES] = NEDGES;
}

// scatter edges into CSR order; epack = (src, coef-bits)
__global__ void fill_kernel(const int* __restrict__ src, const int* __restrict__ dst,
                            const float* __restrict__ dinv, int* __restrict__ cursor,
                            int2* __restrict__ epack, int E) {
    int t = blockIdx.x * blockDim.x + threadIdx.x;
    if (t >= E) return;
    int s = src[t];
    int d = dst[t];
    int pos = atomicAdd(&cursor[d], 1);
    float c = dinv[s] * dinv[d];
    epack[pos] = make_int2(s, __float_as_int(c));
}

// ---------------- GEMM: h[N,128] = x[N,64] @ W[64,128], channel-pair permuted store
// h[i, 2c] = (xW)[i][c] (a-part), h[i, 2c+1] = (xW)[i][c+64] (g-part)

__global__ __launch_bounds__(256) void gemm_kernel(const float* __restrict__ x,
                                                   const float* __restrict__ W,
                                                   float* __restrict__ h) {
    __shared__ float Wl[CH * CH2];   // 32 KB
    __shared__ float Xl[16 * CH];    // 4 KB
    int t = threadIdx.x;

    const float4* W4 = (const float4*)W;
    float4* Wl4 = (float4*)Wl;
#pragma unroll
    for (int i = 0; i < 8; ++i) Wl4[t + 256 * i] = W4[t + 256 * i];

    int row0 = blockIdx.x * 16;
    ((float4*)Xl)[t] = ((const float4*)(x + (size_t)row0 * CH))[t];
    __syncthreads();

    int col = t & 127;
    int rg  = t >> 7;
    float acc[8];
#pragma unroll
    for (int i = 0; i < 8; ++i) acc[i] = 0.0f;

#pragma unroll 4
    for (int k = 0; k < CH; ++k) {
        float w = Wl[k * CH2 + col];
#pragma unroll
        for (int i = 0; i < 8; ++i)
            acc[i] += Xl[(rg * 8 + i) * CH + k] * w;
    }

    int outc = (col < 64) ? (2 * col) : (2 * (col - 64) + 1);
#pragma unroll
    for (int i = 0; i < 8; ++i)
        h[((size_t)row0 + rg * 8 + i) * CH2 + outc] = acc[i];
}

// ---------------- fused aggregate + self-loop + bias + GLU + residual ----------------
// one wave (64 lanes) per node; lane l owns channel pair (a[l], g[l]) = h[.., 2l..2l+1]

__global__ __launch_bounds__(256) void agg_kernel(const int* __restrict__ rowptr,
                                                  const int2* __restrict__ epack,
                                                  const float* __restrict__ h,
                                                  const float* __restrict__ dinv,
                                                  const float* __restrict__ b,
                                                  const float* __restrict__ xold,
                                                  float* __restrict__ xnew) {
    int w = (blockIdx.x * 256 + threadIdx.x) >> 6;   // node id
    int lane = threadIdx.x & 63;
    if (w >= NNODES) return;

    int start = rowptr[w];
    int end   = rowptr[w + 1];
    float2 acc = make_float2(0.0f, 0.0f);

    for (int e = start; e < end; ++e) {
        int2 p = epack[e];                            // uniform across wave (broadcast)
        float c = __int_as_float(p.y);
        float2 hv = *(const float2*)(h + (size_t)p.x * CH2 + 2 * lane);
        acc.x += c * hv.x;
        acc.y += c * hv.y;
    }

    float dv = dinv[w];
    float d2 = dv * dv;
    float2 hs = *(const float2*)(h + (size_t)w * CH2 + 2 * lane);
    float a = acc.x + hs.x * d2 + b[lane];
    float g = acc.y + hs.y * d2 + b[64 + lane];
    float sg = 1.0f / (1.0f + expf(-g));
    xnew[(size_t)w * CH + lane] = a * sg + xold[(size_t)w * CH + lane];
}

// ---------------- launch ----------------

extern "C" void kernel_launch(void* const* d_in, const int* in_sizes, int n_in,
                              void* d_out, int out_size, void* d_ws, size_t ws_size,
                              hipStream_t stream) {
    const float* x_in = (const float*)d_in[0];              // [N,64]
    const float* Ws   = (const float*)d_in[1];              // [3,64,128]
    const float* bs   = (const float*)d_in[2];              // [3,128]
    const int*   ei   = (const int*)d_in[3];                // [2,E] (int32 on device)
    const int* src = ei;
    const int* dst = ei + NEDGES;

    char* wsb = (char*)d_ws;
    int*   cnt    = (int*)wsb;                               // N
    float* dinv   = (float*)(wsb + 1 * 512 * 1024);          // N
    int*   rowptr = (int*)(wsb + 2 * 512 * 1024);            // N+1
    int*   cursor = (int*)(wsb + 3 * 512 * 1024);            // N
    int2*  epack  = (int2*)(wsb + 4 * 512 * 1024);           // E int2 = 12.8 MB
    float* h      = (float*)(wsb + 18 * 1024 * 1024);        // N*128 = 51.2 MB
    float* xbuf   = (float*)(wsb + 72 * 1024 * 1024);        // N*64  = 25.6 MB

    // ---- CSR build (once; reused by all layers) ----
    hipMemsetAsync(cnt, 0, NNODES * sizeof(int), stream);
    hist_kernel<<<(NEDGES + 255) / 256, 256, 0, stream>>>(dst, cnt, NEDGES);
    dinv_kernel<<<(NNODES + 255) / 256, 256, 0, stream>>>(cnt, dinv, NNODES);
    scan_kernel<<<1, SCAN_THREADS, 0, stream>>>(cnt, rowptr, cursor);
    fill_kernel<<<(NEDGES + 255) / 256, 256, 0, stream>>>(src, dst, dinv, cursor, epack, NEDGES);

    const float* xl = x_in;
    for (int l = 0; l < NLAYERS; ++l) {
        const float* W = Ws + (size_t)l * CH * CH2;
        const float* b = bs + (size_t)l * CH2;
        float* xout = (l == NLAYERS - 1) ? (float*)d_out : xbuf;

        gemm_kernel<<<NNODES / 16, 256, 0, stream>>>(xl, W, h);
        agg_kernel<<<(NNODES * 64 + 255) / 256, 256, 0, stream>>>(rowptr, epack, h, dinv, b, xl, xout);

        xl = xout;   // in-place on xbuf for middle layer: each lane reads/writes only its own element
    }
}

// Round 3
// 733.904 us; speedup vs baseline: 11.5462x; 1.5257x over previous
//
#include <hip/hip_runtime.h>
#include <math.h>

#define NNODES 100000
#define NEDGES 1600000
#define CH 64
#define CH2 128
#define NLAYERS 3
#define NBLK 98            // ceil(100000 / 1024) scan blocks

// ---------------- CSR build: histogram over dst ----------------

__global__ void hist_kernel(const int* __restrict__ dst, int* __restrict__ cnt, int E) {
    int t = blockIdx.x * blockDim.x + threadIdx.x;
    if (t < E) atomicAdd(&cnt[dst[t]], 1);
}

__global__ void dinv_kernel(const int* __restrict__ cnt, float* __restrict__ dinv, int n) {
    int t = blockIdx.x * blockDim.x + threadIdx.x;
    if (t < n) dinv[t] = rsqrtf((float)cnt[t] + 1.0f);   // +1 self-loop
}

// ---- 3-pass parallel exclusive scan over cnt[100000] ----

// pass 1: per-block (1024 elems) sum
__global__ __launch_bounds__(256) void bsum_kernel(const int* __restrict__ cnt,
                                                   int* __restrict__ bsum) {
    int t = threadIdx.x;
    int base = blockIdx.x * 1024 + t * 4;
    int s = 0;
#pragma unroll
    for (int i = 0; i < 4; ++i) { int k = base + i; if (k < NNODES) s += cnt[k]; }
    __shared__ int ls[256];
    ls[t] = s; __syncthreads();
    for (int off = 128; off > 0; off >>= 1) {
        if (t < off) ls[t] += ls[t + off];
        __syncthreads();
    }
    if (t == 0) bsum[blockIdx.x] = ls[0];
}

// pass 2: scan the 98 block sums (single small block)
__global__ __launch_bounds__(128) void bscan_kernel(const int* __restrict__ bsum,
                                                    int* __restrict__ boff,
                                                    int* __restrict__ rowptr) {
    __shared__ int s[128];
    int t = threadIdx.x;
    int v = (t < NBLK) ? bsum[t] : 0;
    s[t] = v; __syncthreads();
    for (int off = 1; off < 128; off <<= 1) {
        int u = (t >= off) ? s[t - off] : 0;
        __syncthreads();
        s[t] += u;
        __syncthreads();
    }
    if (t < NBLK) boff[t] = s[t] - v;   // exclusive
    if (t == 0) rowptr[NNODES] = NEDGES;
}

// pass 3: per-block local scan + offset -> rowptr, cursor
__global__ __launch_bounds__(256) void scanb_kernel(const int* __restrict__ cnt,
                                                    const int* __restrict__ boff,
                                                    int* __restrict__ rowptr,
                                                    int* __restrict__ cursor) {
    int t = threadIdx.x;
    int base = blockIdx.x * 1024 + t * 4;
    int v[4]; int tsum = 0;
#pragma unroll
    for (int i = 0; i < 4; ++i) { int k = base + i; v[i] = (k < NNODES) ? cnt[k] : 0; tsum += v[i]; }
    __shared__ int ls[256];
    ls[t] = tsum; __syncthreads();
    for (int off = 1; off < 256; off <<= 1) {
        int u = (t >= off) ? ls[t - off] : 0;
        __syncthreads();
        ls[t] += u;
        __syncthreads();
    }
    int run = boff[blockIdx.x] + ls[t] - tsum;
#pragma unroll
    for (int i = 0; i < 4; ++i) {
        int k = base + i;
        if (k < NNODES) { rowptr[k] = run; cursor[k] = run; run += v[i]; }
    }
}

// scatter edges into CSR order; epack = (src, coef-bits)
__global__ void fill_kernel(const int* __restrict__ src, const int* __restrict__ dst,
                            const float* __restrict__ dinv, int* __restrict__ cursor,
                            int2* __restrict__ epack, int E) {
    int t = blockIdx.x * blockDim.x + threadIdx.x;
    if (t >= E) return;
    int s = src[t];
    int d = dst[t];
    int pos = atomicAdd(&cursor[d], 1);
    float c = dinv[s] * dinv[d];
    epack[pos] = make_int2(s, __float_as_int(c));
}

// ---------------- GEMM: h[N,128] = x[N,64] @ W[64,128], channel-pair permuted store
// h[i, 2c] = (xW)[i][c] (a-part), h[i, 2c+1] = (xW)[i][c+64] (g-part)

__global__ __launch_bounds__(256) void gemm_kernel(const float* __restrict__ x,
                                                   const float* __restrict__ W,
                                                   float* __restrict__ h) {
    __shared__ float Wl[CH * CH2];   // 32 KB
    __shared__ float Xl[16 * CH];    // 4 KB
    int t = threadIdx.x;

    const float4* W4 = (const float4*)W;
    float4* Wl4 = (float4*)Wl;
#pragma unroll
    for (int i = 0; i < 8; ++i) Wl4[t + 256 * i] = W4[t + 256 * i];

    int row0 = blockIdx.x * 16;
    ((float4*)Xl)[t] = ((const float4*)(x + (size_t)row0 * CH))[t];
    __syncthreads();

    int col = t & 127;
    int rg  = t >> 7;
    float acc[8];
#pragma unroll
    for (int i = 0; i < 8; ++i) acc[i] = 0.0f;

#pragma unroll 4
    for (int k = 0; k < CH; ++k) {
        float w = Wl[k * CH2 + col];
#pragma unroll
        for (int i = 0; i < 8; ++i)
            acc[i] += Xl[(rg * 8 + i) * CH + k] * w;
    }

    int outc = (col < 64) ? (2 * col) : (2 * (col - 64) + 1);
#pragma unroll
    for (int i = 0; i < 8; ++i)
        h[((size_t)row0 + rg * 8 + i) * CH2 + outc] = acc[i];
}

// ---------------- fused aggregate + self-loop + bias + GLU + residual ----------------
// one wave per node; lane l owns channel pair (a[l], g[l]) = h[.., 2l..2l+1].
// Edge metadata loaded coalesced (64 records per wave), broadcast via readlane
// so the h-row gather uses an SGPR base.

__global__ __launch_bounds__(256) void agg_kernel(const int* __restrict__ rowptr,
                                                  const int2* __restrict__ epack,
                                                  const float* __restrict__ h,
                                                  const float* __restrict__ dinv,
                                                  const float* __restrict__ b,
                                                  const float* __restrict__ xold,
                                                  float* __restrict__ xnew) {
    int w = (blockIdx.x * 256 + threadIdx.x) >> 6;   // node id
    int lane = threadIdx.x & 63;
    if (w >= NNODES) return;

    int start = rowptr[w];
    int end   = rowptr[w + 1];
    float2 acc = make_float2(0.0f, 0.0f);

    for (int base = start; base < end; base += 64) {
        int m = end - base; if (m > 64) m = 64;
        int2 p = make_int2(0, 0);
        if (lane < m) p = epack[base + lane];        // coalesced 8B/lane
        for (int j = 0; j < m; ++j) {
            int   s = __builtin_amdgcn_readlane(p.x, j);          // SGPR
            float c = __int_as_float(__builtin_amdgcn_readlane(p.y, j));
            float2 hv = *(const float2*)(h + (size_t)s * CH2 + 2 * lane);
            acc.x += c * hv.x;
            acc.y += c * hv.y;
        }
    }

    float dv = dinv[w];
    float d2 = dv * dv;
    float2 hs = *(const float2*)(h + (size_t)w * CH2 + 2 * lane);
    float a = acc.x + hs.x * d2 + b[lane];
    float g = acc.y + hs.y * d2 + b[64 + lane];
    float sg = 1.0f / (1.0f + expf(-g));
    xnew[(size_t)w * CH + lane] = a * sg + xold[(size_t)w * CH + lane];
}

// ---------------- launch ----------------

extern "C" void kernel_launch(void* const* d_in, const int* in_sizes, int n_in,
                              void* d_out, int out_size, void* d_ws, size_t ws_size,
                              hipStream_t stream) {
    const float* x_in = (const float*)d_in[0];              // [N,64]
    const float* Ws   = (const float*)d_in[1];              // [3,64,128]
    const float* bs   = (const float*)d_in[2];              // [3,128]
    const int*   ei   = (const int*)d_in[3];                // [2,E]
    const int* src = ei;
    const int* dst = ei + NEDGES;

    char* wsb = (char*)d_ws;
    int*   cnt    = (int*)wsb;                               // N
    float* dinv   = (float*)(wsb + 1 * 512 * 1024);          // N
    int*   rowptr = (int*)(wsb + 2 * 512 * 1024);            // N+1
    int*   cursor = (int*)(wsb + 3 * 512 * 1024);            // N
    int*   bsum   = (int*)(wsb + 2 * 512 * 1024 + 448 * 1024); // 98 ints (inside rowptr slab tail)
    int*   boff   = bsum + 128;
    int2*  epack  = (int2*)(wsb + 4 * 512 * 1024);           // E int2 = 12.8 MB
    float* h      = (float*)(wsb + 18 * 1024 * 1024);        // N*128 = 51.2 MB
    float* xbuf   = (float*)(wsb + 72 * 1024 * 1024);        // N*64  = 25.6 MB

    // ---- CSR build (once; reused by all layers) ----
    hipMemsetAsync(cnt, 0, NNODES * sizeof(int), stream);
    hist_kernel<<<(NEDGES + 255) / 256, 256, 0, stream>>>(dst, cnt, NEDGES);
    dinv_kernel<<<(NNODES + 255) / 256, 256, 0, stream>>>(cnt, dinv, NNODES);
    bsum_kernel<<<NBLK, 256, 0, stream>>>(cnt, bsum);
    bscan_kernel<<<1, 128, 0, stream>>>(bsum, boff, rowptr);
    scanb_kernel<<<NBLK, 256, 0, stream>>>(cnt, boff, rowptr, cursor);
    fill_kernel<<<(NEDGES + 255) / 256, 256, 0, stream>>>(src, dst, dinv, cursor, epack, NEDGES);

    const float* xl = x_in;
    for (int l = 0; l < NLAYERS; ++l) {
        const float* W = Ws + (size_t)l * CH * CH2;
        const float* b = bs + (size_t)l * CH2;
        float* xout = (l == NLAYERS - 1) ? (float*)d_out : xbuf;

        gemm_kernel<<<NNODES / 16, 256, 0, stream>>>(xl, W, h);
        agg_kernel<<<(NNODES * 64 + 255) / 256, 256, 0, stream>>>(rowptr, epack, h, dinv, b, xl, xout);

        xl = xout;   // in-place on xbuf for middle layer: each lane touches only its own element
    }
}

// Round 4
// 654.525 us; speedup vs baseline: 12.9465x; 1.1213x over previous
//
#include <hip/hip_runtime.h>
#include <math.h>

#define NNODES 100000
#define NEDGES 1600000
#define CH 64
#define CH2 128
#define NLAYERS 3
#define NBLK 98            // ceil(100000 / 1024) scan blocks

// ---------------- CSR build: histogram over dst ----------------

__global__ void hist_kernel(const int* __restrict__ dst, int* __restrict__ cnt, int E) {
    int t = blockIdx.x * blockDim.x + threadIdx.x;
    if (t < E) atomicAdd(&cnt[dst[t]], 1);
}

__global__ void dinv_kernel(const int* __restrict__ cnt, float* __restrict__ dinv, int n) {
    int t = blockIdx.x * blockDim.x + threadIdx.x;
    if (t < n) dinv[t] = rsqrtf((float)cnt[t] + 1.0f);   // +1 self-loop
}

// ---- 3-pass parallel exclusive scan over cnt[100000] ----

__global__ __launch_bounds__(256) void bsum_kernel(const int* __restrict__ cnt,
                                                   int* __restrict__ bsum) {
    int t = threadIdx.x;
    int base = blockIdx.x * 1024 + t * 4;
    int s = 0;
#pragma unroll
    for (int i = 0; i < 4; ++i) { int k = base + i; if (k < NNODES) s += cnt[k]; }
    __shared__ int ls[256];
    ls[t] = s; __syncthreads();
    for (int off = 128; off > 0; off >>= 1) {
        if (t < off) ls[t] += ls[t + off];
        __syncthreads();
    }
    if (t == 0) bsum[blockIdx.x] = ls[0];
}

__global__ __launch_bounds__(128) void bscan_kernel(const int* __restrict__ bsum,
                                                    int* __restrict__ boff,
                                                    int* __restrict__ rowptr) {
    __shared__ int s[128];
    int t = threadIdx.x;
    int v = (t < NBLK) ? bsum[t] : 0;
    s[t] = v; __syncthreads();
    for (int off = 1; off < 128; off <<= 1) {
        int u = (t >= off) ? s[t - off] : 0;
        __syncthreads();
        s[t] += u;
        __syncthreads();
    }
    if (t < NBLK) boff[t] = s[t] - v;   // exclusive
    if (t == 0) rowptr[NNODES] = NEDGES;
}

__global__ __launch_bounds__(256) void scanb_kernel(const int* __restrict__ cnt,
                                                    const int* __restrict__ boff,
                                                    int* __restrict__ rowptr,
                                                    int* __restrict__ cursor) {
    int t = threadIdx.x;
    int base = blockIdx.x * 1024 + t * 4;
    int v[4]; int tsum = 0;
#pragma unroll
    for (int i = 0; i < 4; ++i) { int k = base + i; v[i] = (k < NNODES) ? cnt[k] : 0; tsum += v[i]; }
    __shared__ int ls[256];
    ls[t] = tsum; __syncthreads();
    for (int off = 1; off < 256; off <<= 1) {
        int u = (t >= off) ? ls[t - off] : 0;
        __syncthreads();
        ls[t] += u;
        __syncthreads();
    }
    int run = boff[blockIdx.x] + ls[t] - tsum;
#pragma unroll
    for (int i = 0; i < 4; ++i) {
        int k = base + i;
        if (k < NNODES) { rowptr[k] = run; cursor[k] = run; run += v[i]; }
    }
}

// scatter edges into CSR order; epack = (src, coef-bits)
__global__ void fill_kernel(const int* __restrict__ src, const int* __restrict__ dst,
                            const float* __restrict__ dinv, int* __restrict__ cursor,
                            int2* __restrict__ epack, int E) {
    int t = blockIdx.x * blockDim.x + threadIdx.x;
    if (t >= E) return;
    int s = src[t];
    int d = dst[t];
    int pos = atomicAdd(&cursor[d], 1);
    float c = dinv[s] * dinv[d];
    epack[pos] = make_int2(s, __float_as_int(c));
}

// ---------------- aggregate on INPUT channels: z = A_norm @ x + d^2 * x ----------------
// (A @ (xW) == (A @ x) @ W -- aggregate first, project after: halves gather bytes)
// one wave per node; lane owns one channel (4B/lane, 256B contiguous per edge row).

__global__ __launch_bounds__(256) void aggx_kernel(const int* __restrict__ rowptr,
                                                   const int2* __restrict__ epack,
                                                   const float* __restrict__ x,
                                                   const float* __restrict__ dinv,
                                                   float* __restrict__ z) {
    int w = (blockIdx.x * 256 + threadIdx.x) >> 6;   // node id
    int lane = threadIdx.x & 63;
    if (w >= NNODES) return;

    int start = rowptr[w];
    int end   = rowptr[w + 1];
    float acc = 0.0f;

    for (int base = start; base < end; base += 64) {
        int m = end - base; if (m > 64) m = 64;
        int2 p = make_int2(0, 0);
        if (lane < m) p = epack[base + lane];        // coalesced 8B/lane
        for (int j = 0; j < m; ++j) {
            int   s = __builtin_amdgcn_readlane(p.x, j);           // SGPR base
            float c = __int_as_float(__builtin_amdgcn_readlane(p.y, j));
            acc += c * x[(size_t)s * CH + lane];     // 256B coalesced row gather
        }
    }

    float dv = dinv[w];
    acc += dv * dv * x[(size_t)w * CH + lane];       // self-loop
    z[(size_t)w * CH + lane] = acc;
}

// ---------------- fused GEMM + bias + GLU + residual ----------------
// x_next = (z@W)[:, :64]+b_a  *  sigmoid((z@W)[:, 64:]+b_g)  +  x_old
// 256 threads / block, 16 rows; thread owns channel c for 4 rows (both a and g parts).

__global__ __launch_bounds__(256) void gemm_glu_kernel(const float* __restrict__ z,
                                                       const float* __restrict__ W,
                                                       const float* __restrict__ b,
                                                       const float* __restrict__ xold,
                                                       float* __restrict__ xnew) {
    __shared__ float Wl[CH * CH2];   // 32 KB
    __shared__ float Zl[16 * CH];    // 4 KB
    int t = threadIdx.x;

    const float4* W4 = (const float4*)W;
    float4* Wl4 = (float4*)Wl;
#pragma unroll
    for (int i = 0; i < 8; ++i) Wl4[t + 256 * i] = W4[t + 256 * i];

    int row0 = blockIdx.x * 16;
    ((float4*)Zl)[t] = ((const float4*)(z + (size_t)row0 * CH))[t];
    __syncthreads();

    int c  = t & 63;          // channel
    int rg = t >> 6;          // 0..3 -> rows rg*4 .. rg*4+3
    float accA[4] = {0.f, 0.f, 0.f, 0.f};
    float accG[4] = {0.f, 0.f, 0.f, 0.f};

#pragma unroll 4
    for (int k = 0; k < CH; ++k) {
        float wa = Wl[k * CH2 + c];        // conflict-free: lanes consecutive
        float wg = Wl[k * CH2 + 64 + c];
#pragma unroll
        for (int i = 0; i < 4; ++i) {
            float zv = Zl[(rg * 4 + i) * CH + k];   // broadcast within wave
            accA[i] += zv * wa;
            accG[i] += zv * wg;
        }
    }

    float ba = b[c], bg = b[64 + c];
#pragma unroll
    for (int i = 0; i < 4; ++i) {
        size_t idx = ((size_t)row0 + rg * 4 + i) * CH + c;
        float a = accA[i] + ba;
        float g = accG[i] + bg;
        float sg = 1.0f / (1.0f + expf(-g));
        xnew[idx] = a * sg + xold[idx];
    }
}

// ---------------- launch ----------------

extern "C" void kernel_launch(void* const* d_in, const int* in_sizes, int n_in,
                              void* d_out, int out_size, void* d_ws, size_t ws_size,
                              hipStream_t stream) {
    const float* x_in = (const float*)d_in[0];              // [N,64]
    const float* Ws   = (const float*)d_in[1];              // [3,64,128]
    const float* bs   = (const float*)d_in[2];              // [3,128]
    const int*   ei   = (const int*)d_in[3];                // [2,E]
    const int* src = ei;
    const int* dst = ei + NEDGES;

    char* wsb = (char*)d_ws;
    int*   cnt    = (int*)wsb;                                 // N ints
    float* dinv   = (float*)(wsb + 1 * 512 * 1024);            // N floats
    int*   rowptr = (int*)(wsb + 2 * 512 * 1024);              // N+1
    int*   bsum   = (int*)(wsb + 2 * 512 * 1024 + 448 * 1024); // 98 ints (rowptr slab tail)
    int*   boff   = bsum + 128;
    int*   cursor = (int*)(wsb + 3 * 512 * 1024);              // N
    int2*  epack  = (int2*)(wsb + 4 * 512 * 1024);             // E int2 = 12.8 MB
    float* z      = (float*)(wsb + 16 * 1024 * 1024);          // N*64 = 25.6 MB
    float* xbuf   = (float*)(wsb + 48 * 1024 * 1024);          // N*64 = 25.6 MB

    // ---- CSR build (once; reused by all layers) ----
    hipMemsetAsync(cnt, 0, NNODES * sizeof(int), stream);
    hist_kernel<<<(NEDGES + 255) / 256, 256, 0, stream>>>(dst, cnt, NEDGES);
    dinv_kernel<<<(NNODES + 255) / 256, 256, 0, stream>>>(cnt, dinv, NNODES);
    bsum_kernel<<<NBLK, 256, 0, stream>>>(cnt, bsum);
    bscan_kernel<<<1, 128, 0, stream>>>(bsum, boff, rowptr);
    scanb_kernel<<<NBLK, 256, 0, stream>>>(cnt, boff, rowptr, cursor);
    fill_kernel<<<(NEDGES + 255) / 256, 256, 0, stream>>>(src, dst, dinv, cursor, epack, NEDGES);

    const float* xl = x_in;
    for (int l = 0; l < NLAYERS; ++l) {
        const float* W = Ws + (size_t)l * CH * CH2;
        const float* b = bs + (size_t)l * CH2;
        float* xout = (l == NLAYERS - 1) ? (float*)d_out : xbuf;

        aggx_kernel<<<(NNODES * 64 + 255) / 256, 256, 0, stream>>>(rowptr, epack, xl, dinv, z);
        gemm_glu_kernel<<<NNODES / 16, 256, 0, stream>>>(z, W, b, xl, xout);

        xl = xout;   // middle layer runs in-place on xbuf: each element read+written by one thread
    }
}